// Round 8
// baseline (151.250 us; speedup 1.0000x reference)
//
#include <hip/hip_runtime.h>

// GCN forward, algebraically collapsed (no nonlinearity between convs, mean pool):
//   g = (1/n)*((A^T u)^T X)@W1@W2 + (1/n)*(sum u)*(b1@W2) + b2,  A = D^-1/2(Adj+I)D^-1/2
// Round 16: re-tile node-side kernels for machine width (r6 profile: contract
// body ran at 13% occupancy on 157 blocks). F0/F1/contract now 313 blocks x
// 64-node tiles (range split R0=10240 is tile-aligned), float4 replica fold
// (2 vector loads/thread vs 16 scalar), two-stage LDS tree. Scatters, M
// precompute, head, and the 7-kernel pipeline unchanged from 146.9us r15.
// Structural map (do NOT revisit): 256-block spin barriers ~16-24us each
// (r9/r11); contended global atomics ~18 Gop/s (r12); staggered atomic
// writeout (r13); last-block ticket+fence tail (+40us, r14).

#define D_IN 128
#define D_HID 256
#define D_DENSE 128
#define R0 10240          // range-0 bins (40 KB LDS); R0 % 64 == 0
#define NSL 128           // edge slices == replicas per range
#define NT64 313          // ceil(20000/64) 64-node tiles (fold + contract)
#define NTILE NT64

// ---- edge scatter: block = (slice, range); LDS histogram of own range -----
// mode 0: bin[tgt[e]] += w[e]
// mode 1: bin[tgt[e]] += w[e]*dinv[src[e]]
// mode 2: bin[tgt[e]] += w[e]*du[src[e]]            (du = dinv*u)
__global__ __launch_bounds__(1024) void k_scatter(
    const int* __restrict__ tgt, const int* __restrict__ src,
    const float* __restrict__ w, const float* __restrict__ dinv,
    const float* __restrict__ du, float* __restrict__ part,
    int E, int N, int mode) {
    __shared__ __align__(16) float acc[R0];
    const int range = blockIdx.x & 1;
    const int slice = blockIdx.x >> 1;           // 0..NSL-1
    const int base  = range ? R0 : 0;
    const int lim   = range ? (N - R0) : R0;     // 10240 / 9760, both %4==0
    const int per = (E + NSL - 1) / NSL;         // 5000
    const int e0 = slice * per, e1 = min(e0 + per, E);
    float* outp = part + (range ? (size_t)NSL * R0 + (size_t)slice * lim
                                : (size_t)slice * lim);
    for (int i = threadIdx.x * 4; i < lim; i += 4096)
        *(float4*)&acc[i] = make_float4(0.f, 0.f, 0.f, 0.f);
    __syncthreads();
    for (int e = e0 + threadIdx.x; e < e1; e += 1024) {
        int t = tgt[e] - base;
        if ((unsigned)t < (unsigned)lim) {
            float v = w[e];
            if (mode == 1)      v *= dinv[src[e]];
            else if (mode == 2) v *= du[src[e]];
            atomicAdd(&acc[t], v);               // LDS atomic
        }
    }
    __syncthreads();
    for (int i = threadIdx.x * 4; i < lim; i += 4096)
        *(float4*)&outp[i] = *(const float4*)&acc[i];
}

// ---- float4 replica fold core: returns tot4 for nodes i0+4*(tid&15)+[0,4) --
// sh4 usage: [0,1024) stage0, [1024,1280) stage1. Caller syncs after.
__device__ __forceinline__ float4 fold64(
    const float* __restrict__ part, float4* sh4, int i0, int N, int tid)
{
    const int f4s = tid & 15;                    // node group (4 nodes)
    const int rg  = tid >> 4;                    // 0..63 -> replicas 2rg,2rg+1
    const int i   = i0 + f4s * 4;
    size_t st; const float* pp;
    if (i0 < R0) { st = R0;               pp = part + i; }
    else         { st = (size_t)(N - R0); pp = part + (size_t)NSL * R0 + (i - R0); }
    // OOB node groups (last tile) read garbage; masked per-component by caller.
    const float* p0 = pp + (size_t)(2 * rg) * st;
    float4 a = *(const float4*)p0;
    float4 b = *(const float4*)(p0 + st);
    a.x += b.x; a.y += b.y; a.z += b.z; a.w += b.w;
    sh4[rg * 16 + f4s] = a;
    __syncthreads();
    if (tid < 256) {                             // stage1: 64 -> 16
        int rg8 = tid >> 4, s = tid & 15;
        float4 s0 = sh4[((rg8 << 2) + 0) * 16 + s];
        float4 s1 = sh4[((rg8 << 2) + 1) * 16 + s];
        float4 s2 = sh4[((rg8 << 2) + 2) * 16 + s];
        float4 s3 = sh4[((rg8 << 2) + 3) * 16 + s];
        s0.x += s1.x + s2.x + s3.x; s0.y += s1.y + s2.y + s3.y;
        s0.z += s1.z + s2.z + s3.z; s0.w += s1.w + s2.w + s3.w;
        sh4[1024 + rg8 * 16 + s] = s0;
    }
    __syncthreads();
    float4 tot = make_float4(0.f, 0.f, 0.f, 0.f);
    if (tid < 16) {                              // stage2: 16 -> 1
        #pragma unroll
        for (int j = 0; j < 16; ++j) {
            float4 v = sh4[1024 + j * 16 + tid];
            tot.x += v.x; tot.y += v.y; tot.z += v.z; tot.w += v.w;
        }
    }
    return tot;
}

// ---- fold kernel: 64-node tiles; mode-0 spare blocks compute M=W1@W2 -------
__global__ __launch_bounds__(1024) void k_fold(
    const float* __restrict__ part, float* __restrict__ dinv,
    float* __restrict__ du, float* __restrict__ S_u_part,
    const float* __restrict__ W1, const float* __restrict__ b1,
    const float* __restrict__ W2, float* __restrict__ M, float* __restrict__ c2,
    int N, int mode) {
    __shared__ __align__(16) float4 sh4[1280];
    float* lds = (float*)sh4;
    const int b = blockIdx.x, tid = threadIdx.x;

    if (b >= NT64) {                             // ---- M / c2 precompute ----
        int q = b - NT64;                        // 0..63: 4 cols of M each
        lds[tid] = W2[(tid >> 2) * 256 + q * 4 + (tid & 3)];
        __syncthreads();
        int wvi = tid >> 6, lane = tid & 63;
        for (int kr = 0; kr < 8; ++kr) {
            int k = wvi * 8 + kr;                // 16 waves x 8 = 128 rows
            float a0 = 0, a1 = 0, a2 = 0, a3 = 0;
            #pragma unroll
            for (int it = 0; it < 4; ++it) {
                int j = it * 64 + lane;
                float a = W1[k * 256 + j];
                a0 += a * lds[j*4+0]; a1 += a * lds[j*4+1];
                a2 += a * lds[j*4+2]; a3 += a * lds[j*4+3];
            }
            #pragma unroll
            for (int off = 32; off > 0; off >>= 1) {
                a0 += __shfl_down(a0, off, 64); a1 += __shfl_down(a1, off, 64);
                a2 += __shfl_down(a2, off, 64); a3 += __shfl_down(a3, off, 64);
            }
            if (lane == 0) {
                M[k * 256 + q*4 + 0] = a0; M[k * 256 + q*4 + 1] = a1;
                M[k * 256 + q*4 + 2] = a2; M[k * 256 + q*4 + 3] = a3;
            }
        }
        if (wvi == 0) {                          // c2 = b1 @ W2 slab
            float a0 = 0, a1 = 0, a2 = 0, a3 = 0;
            #pragma unroll
            for (int it = 0; it < 4; ++it) {
                int j = it * 64 + lane;
                float a = b1[j];
                a0 += a * lds[j*4+0]; a1 += a * lds[j*4+1];
                a2 += a * lds[j*4+2]; a3 += a * lds[j*4+3];
            }
            #pragma unroll
            for (int off = 32; off > 0; off >>= 1) {
                a0 += __shfl_down(a0, off, 64); a1 += __shfl_down(a1, off, 64);
                a2 += __shfl_down(a2, off, 64); a3 += __shfl_down(a3, off, 64);
            }
            if (lane == 0) {
                c2[q*4+0] = a0; c2[q*4+1] = a1;
                c2[q*4+2] = a2; c2[q*4+3] = a3;
            }
        }
        return;
    }

    const int i0 = b * 64;
    float4 tot = fold64(part, sh4, i0, N, tid);
    const int i = i0 + tid * 4;                  // valid for tid<16
    float s = 0.f;
    if (tid < 16 && i < N) {                     // N%4==0: whole f4 valid
        if (mode == 0) {
            float4 dv;
            dv.x = rsqrtf(tot.x + 1.0f); dv.y = rsqrtf(tot.y + 1.0f);
            dv.z = rsqrtf(tot.z + 1.0f); dv.w = rsqrtf(tot.w + 1.0f);
            *(float4*)(dinv + i) = dv;
        } else {
            float4 d = *(const float4*)(dinv + i);
            float4 ui, duv;
            ui.x = d.x * (tot.x + d.x); ui.y = d.y * (tot.y + d.y);
            ui.z = d.z * (tot.z + d.z); ui.w = d.w * (tot.w + d.w);
            duv.x = d.x * ui.x; duv.y = d.y * ui.y;
            duv.z = d.z * ui.z; duv.w = d.w * ui.w;
            *(float4*)(du + i) = duv;
            s = ui.x + ui.y + ui.z + ui.w;
        }
    }
    if (mode == 1) {                             // S_u partial (wave 0 only)
        if (tid < 64) {
            #pragma unroll
            for (int off = 32; off > 0; off >>= 1) s += __shfl_down(s, off, 64);
            if (tid == 0) S_u_part[b] = s;
        }
    }
}

// ---- contraction: 64-node tiles, fold wv + contract against x --------------
__global__ __launch_bounds__(1024) void k_contract(
    const float* __restrict__ x, const float* __restrict__ part,
    const float* __restrict__ dinv, const float* __restrict__ du,
    float* __restrict__ s_part, int N) {
    __shared__ __align__(16) float4 sh4[1280];
    float* shc = (float*)sh4;                    // scalar alias [0,1024)
    float* wvl = ((float*)sh4) + 4096;           // [4096,4160) = sh4[1024..]
    const int b = blockIdx.x, tid = threadIdx.x;
    const int i0 = b * 64;
    float4 tot = fold64(part, sh4, i0, N, tid);
    // wvl[64]: note wvl aliases sh4[1024..1039], whose last READ was stage2
    // (tid<16) inside fold64; must complete before overwrite.
    __syncthreads();
    if (tid < 16) {
        const int i = i0 + tid * 4;
        float4 wv = make_float4(0.f, 0.f, 0.f, 0.f);
        if (i < N) {
            float4 d  = *(const float4*)(dinv + i);
            float4 dv = *(const float4*)(du + i);
            wv.x = d.x * (tot.x + dv.x); wv.y = d.y * (tot.y + dv.y);
            wv.z = d.z * (tot.z + dv.z); wv.w = d.w * (tot.w + dv.w);
        }
        *(float4*)(wvl + tid * 4) = wv;          // OOB nodes -> 0 mask
    }
    __syncthreads();
    // contraction: k = tid&127 feature, rg = tid>>7 row group (8 rows each)
    const int k = tid & 127, rg = tid >> 7;
    float a = 0.f;
    #pragma unroll
    for (int j = 0; j < 8; ++j) {
        int m = rg * 8 + j;
        int i2 = i0 + m;
        float xv = x[(size_t)(i2 < N ? i2 : 0) * D_IN + k];  // clamped; wvl=0 masks
        a += wvl[m] * xv;
    }
    __syncthreads();                             // shc aliases sh4 stage0
    shc[tid] = a;
    __syncthreads();
    if (rg == 0) {
        float t2s = 0.f;
        #pragma unroll
        for (int t2 = 0; t2 < 8; ++t2) t2s += shc[t2 * 128 + k];
        s_part[b * 128 + k] = t2s;
    }
}

// ---- head: fold s + S_u, g = s@M, z = relu(g@Wd1), logits, softmax --------
__global__ __launch_bounds__(1024) void k_head(
    const float* __restrict__ s_part, const float* __restrict__ S_u_part,
    const float* __restrict__ M, const float* __restrict__ c2,
    const float* __restrict__ b2, const float* __restrict__ Wd1,
    const float* __restrict__ bd1, const float* __restrict__ Wd2,
    const float* __restrict__ bd2, float* __restrict__ out, float inv_n) {
    __shared__ float sh[1024];
    __shared__ float ss[128];
    __shared__ float gv[256];
    __shared__ float zz[128];
    __shared__ float su[16];
    __shared__ float S_u_s;
    const int tid = threadIdx.x;
    const int k = tid & 127, rg = tid >> 7;      // rg in [0,8)

    // ---- fold s_part over NT64 tiles; S_u over NT64 partials concurrently -
    float a2 = 0.f;
    for (int q = rg; q < NTILE; q += 8) a2 += s_part[q * 128 + k];
    float v = (tid < NT64) ? S_u_part[tid] : 0.f;
    #pragma unroll
    for (int off = 32; off > 0; off >>= 1) v += __shfl_down(v, off, 64);
    sh[tid] = a2;
    if ((tid & 63) == 0) su[tid >> 6] = v;
    __syncthreads();
    if (rg == 0) {
        float t2 = 0.f;
        #pragma unroll
        for (int q = 0; q < 8; ++q) t2 += sh[q * 128 + k];
        ss[k] = t2;                              // s[k]
    }
    if (tid == 0) {
        float t2 = 0.f;
        #pragma unroll
        for (int q = 0; q < 16; ++q) t2 += su[q];
        S_u_s = t2;
    }
    __syncthreads();

    // ---- g[t] = (sum_k ss[k]*M[k*256+t] + S_u*c2[t])*inv_n + b2[t] --------
    {
        const int t = tid & 255, p = tid >> 8;   // p in [0,4): k-range p*32..
        float gp = 0.f;
        #pragma unroll
        for (int kk = 0; kk < 32; ++kk)
            gp += ss[p * 32 + kk] * M[(p * 32 + kk) * 256 + t];
        sh[tid] = gp;
    }
    __syncthreads();
    if (tid < 256) {
        float gval = sh[tid] + sh[256 + tid] + sh[512 + tid] + sh[768 + tid];
        gv[tid] = (gval + S_u_s * c2[tid]) * inv_n + b2[tid];
    }
    __syncthreads();

    // ---- z[j] = relu(sum_t gv[t]*Wd1[t*128+j] + bd1[j]) -------------------
    {
        const int j = tid & 127, p = tid >> 7;   // p in [0,8): t-range p*32..
        float zp = 0.f;
        #pragma unroll
        for (int t2 = 0; t2 < 32; ++t2)
            zp += gv[p * 32 + t2] * Wd1[(p * 32 + t2) * D_DENSE + j];
        sh[tid] = zp;
    }
    __syncthreads();
    if (tid < 128) {
        float z = bd1[tid];
        #pragma unroll
        for (int p2 = 0; p2 < 8; ++p2) z += sh[p2 * 128 + tid];
        zz[tid] = fmaxf(z, 0.f);
    }
    __syncthreads();

    // ---- logits + softmax -------------------------------------------------
    float p0 = 0.f, p1 = 0.f;
    if (tid < 128) {
        p0 = zz[tid] * Wd2[tid * 2 + 0];
        p1 = zz[tid] * Wd2[tid * 2 + 1];
    }
    #pragma unroll
    for (int off = 32; off > 0; off >>= 1) {
        p0 += __shfl_down(p0, off, 64);
        p1 += __shfl_down(p1, off, 64);
    }
    if ((tid & 63) == 0) { sh[tid >> 6] = p0; sh[32 + (tid >> 6)] = p1; }
    __syncthreads();
    if (tid == 0) {
        float l0 = bd2[0], l1 = bd2[1];
        #pragma unroll
        for (int q = 0; q < 16; ++q) { l0 += sh[q]; l1 += sh[32 + q]; }
        float m = fmaxf(l0, l1);
        float e0 = expf(l0 - m), e1 = expf(l1 - m);
        float inv = 1.0f / (e0 + e1);
        out[0] = e0 * inv;
        out[1] = e1 * inv;
    }
}

extern "C" void kernel_launch(void* const* d_in, const int* in_sizes, int n_in,
                              void* d_out, int out_size, void* d_ws, size_t ws_size,
                              hipStream_t stream) {
    const float* x   = (const float*)d_in[0];
    const int*   ei  = (const int*)  d_in[1];
    const float* w   = (const float*)d_in[2];
    const float* W1  = (const float*)d_in[3];
    const float* b1  = (const float*)d_in[4];
    const float* W2  = (const float*)d_in[5];
    const float* b2  = (const float*)d_in[6];
    const float* Wd1 = (const float*)d_in[7];
    const float* bd1 = (const float*)d_in[8];
    const float* Wd2 = (const float*)d_in[9];
    const float* bd2 = (const float*)d_in[10];
    float* out = (float*)d_out;

    const int N = in_sizes[0] / D_IN;      // 20000
    const int E = in_sizes[1] / 2;         // 640000
    const int* row = ei;
    const int* col = ei + E;

    // workspace layout (every word written before read; no ctr, no memset).
    // NOTE: fold/contract f4 reads may run up to 28 floats past part's end on
    // the last tile; pad part region by 32 floats (values masked, never used).
    float* fws    = (float*)d_ws;
    float* part   = fws;                                   // NSL*N (+32 pad)
    float* dinv   = part + (size_t)NSL * N + 32;           // N
    float* du     = dinv + N;                              // N (dinv*u)
    float* s_part = du + N;                                // NT64*128
    float* S_u_p  = s_part + (size_t)NT64 * D_IN;          // NT64
    float* M      = S_u_p + NT64;                          // 128*256
    float* c2     = M + D_IN * D_HID;                      // 256

    // pass 1: deg by col -> dinv; spare fold blocks compute M=W1@W2, c2=b1@W2
    k_scatter<<<2 * NSL, 1024, 0, stream>>>(col, row, w, dinv, du, part, E, N, 0);
    k_fold<<<NT64 + 64, 1024, 0, stream>>>(part, dinv, du, S_u_p, W1, b1, W2, M, c2, N, 0);
    // pass 2: by row, gather dinv[col] -> du, S_u partials
    k_scatter<<<2 * NSL, 1024, 0, stream>>>(row, col, w, dinv, du, part, E, N, 1);
    k_fold<<<NT64, 1024, 0, stream>>>(part, dinv, du, S_u_p, W1, b1, W2, M, c2, N, 1);
    // pass 3: by row, gather du[col] (single gather)
    k_scatter<<<2 * NSL, 1024, 0, stream>>>(row, col, w, dinv, du, part, E, N, 2);
    // wv-fold + feature contraction (barrier-free), then 1-block head
    k_contract<<<NT64, 1024, 0, stream>>>(x, part, dinv, du, s_part, N);
    k_head<<<1, 1024, 0, stream>>>(s_part, S_u_p, M, c2, b2, Wd1, bd1, Wd2, bd2,
                                   out, 1.0f / (float)N);
}

// Round 9
// 146.118 us; speedup vs baseline: 1.0351x; 1.0351x over previous
//
#include <hip/hip_runtime.h>

// GCN forward, algebraically collapsed (no nonlinearity between convs, mean pool):
//   g = (1/n)*((A^T u)^T X)@W1@W2 + (1/n)*(sum u)*(b1@W2) + b2,  A = D^-1/2(Adj+I)D^-1/2
// Round 17: r15 (146.9us, best) + ONE change: vectorized scatter edge loop
// (4 edges/thread, int4/float4 loads; slice size 5000%4==0, no tail).
// r1 evidence: phase work ~59us vs ~11us of HBM traffic => issue/latency-bound;
// the scalar 3-loads-per-edge scatter loop is the main issue-bound consumer.
// r16 (64-node tiles + float4 fold) REGRESSED (+4.3us): node-side kernels are
// launch-floored; reverted.
// Structural map (do NOT revisit): 256-block spin barriers ~16-24us each
// (r9/r11); contended global atomics ~18 Gop/s (r12); staggered atomic
// writeout (r13); last-block ticket+fence tail (+40us, r14); node-side
// re-tiling (r16).

#define D_IN 128
#define D_HID 256
#define D_DENSE 128
#define R0 10240          // range-0 bins (40 KB LDS)
#define NSL 128           // edge slices == replicas per range
#define NFOLD 250         // fold blocks (FOLD_C nodes each)
#define FOLD_C 80
#define NTILE 157         // ceil(20000/128) contraction tiles

// ---- edge scatter: block = (slice, range); LDS histogram of own range -----
// mode 0: bin[tgt[e]] += w[e]
// mode 1: bin[tgt[e]] += w[e]*dinv[src[e]]
// mode 2: bin[tgt[e]] += w[e]*du[src[e]]            (du = dinv*u)
// Edge loop vectorized 4-wide: slice bounds are multiples of 4 (5000, E=640000).
__global__ __launch_bounds__(1024) void k_scatter(
    const int* __restrict__ tgt, const int* __restrict__ src,
    const float* __restrict__ w, const float* __restrict__ dinv,
    const float* __restrict__ du, float* __restrict__ part,
    int E, int N, int mode) {
    __shared__ __align__(16) float acc[R0];
    const int range = blockIdx.x & 1;
    const int slice = blockIdx.x >> 1;           // 0..NSL-1
    const int base  = range ? R0 : 0;
    const int lim   = range ? (N - R0) : R0;     // 10240 / 9760, both %4==0
    const int per = (E + NSL - 1) / NSL;         // 5000 (%4==0)
    const int e0 = slice * per, e1 = min(e0 + per, E);
    float* outp = part + (range ? (size_t)NSL * R0 + (size_t)slice * lim
                                : (size_t)slice * lim);
    for (int i = threadIdx.x * 4; i < lim; i += 4096)
        *(float4*)&acc[i] = make_float4(0.f, 0.f, 0.f, 0.f);
    __syncthreads();
    const int v0 = e0 >> 2, v1 = e1 >> 2;        // 4-edge vectors
    const int4*   tgt4 = (const int4*)tgt;
    const int4*   src4 = (const int4*)src;
    const float4* wp4  = (const float4*)w;
    for (int v = v0 + threadIdx.x; v < v1; v += 1024) {
        int4   t4 = tgt4[v];
        float4 w4 = wp4[v];
        float m0 = w4.x, m1 = w4.y, m2 = w4.z, m3 = w4.w;
        if (mode == 1) {                         // unconditional L2 gathers
            int4 s4 = src4[v];
            m0 *= dinv[s4.x]; m1 *= dinv[s4.y];
            m2 *= dinv[s4.z]; m3 *= dinv[s4.w];
        } else if (mode == 2) {
            int4 s4 = src4[v];
            m0 *= du[s4.x]; m1 *= du[s4.y];
            m2 *= du[s4.z]; m3 *= du[s4.w];
        }
        int a0 = t4.x - base, a1 = t4.y - base;
        int a2 = t4.z - base, a3 = t4.w - base;
        if ((unsigned)a0 < (unsigned)lim) atomicAdd(&acc[a0], m0);
        if ((unsigned)a1 < (unsigned)lim) atomicAdd(&acc[a1], m1);
        if ((unsigned)a2 < (unsigned)lim) atomicAdd(&acc[a2], m2);
        if ((unsigned)a3 < (unsigned)lim) atomicAdd(&acc[a3], m3);
    }
    __syncthreads();
    for (int i = threadIdx.x * 4; i < lim; i += 4096)
        *(float4*)&outp[i] = *(const float4*)&acc[i];
}

// ---- fold 128 replicas + node math (modes 0,1); mode-0 spare blocks: M=W1@W2
__global__ __launch_bounds__(1024) void k_fold(
    const float* __restrict__ part, float* __restrict__ dinv,
    float* __restrict__ du, float* __restrict__ S_u_part,
    const float* __restrict__ W1, const float* __restrict__ b1,
    const float* __restrict__ W2, float* __restrict__ M, float* __restrict__ c2,
    int N, int mode) {
    __shared__ float lds[1044];
    const int b = blockIdx.x, tid = threadIdx.x;

    if (b >= NFOLD) {                            // ---- M / c2 precompute ----
        int q = b - NFOLD;                       // 0..63: 4 cols of M each
        lds[tid] = W2[(tid >> 2) * 256 + q * 4 + (tid & 3)];
        __syncthreads();
        int wvi = tid >> 6, lane = tid & 63;
        for (int kr = 0; kr < 8; ++kr) {
            int k = wvi * 8 + kr;                // 16 waves x 8 = 128 rows
            float a0 = 0, a1 = 0, a2 = 0, a3 = 0;
            #pragma unroll
            for (int it = 0; it < 4; ++it) {
                int j = it * 64 + lane;
                float a = W1[k * 256 + j];
                a0 += a * lds[j*4+0]; a1 += a * lds[j*4+1];
                a2 += a * lds[j*4+2]; a3 += a * lds[j*4+3];
            }
            #pragma unroll
            for (int off = 32; off > 0; off >>= 1) {
                a0 += __shfl_down(a0, off, 64); a1 += __shfl_down(a1, off, 64);
                a2 += __shfl_down(a2, off, 64); a3 += __shfl_down(a3, off, 64);
            }
            if (lane == 0) {
                M[k * 256 + q*4 + 0] = a0; M[k * 256 + q*4 + 1] = a1;
                M[k * 256 + q*4 + 2] = a2; M[k * 256 + q*4 + 3] = a3;
            }
        }
        if (wvi == 0) {                          // c2 = b1 @ W2 slab
            float a0 = 0, a1 = 0, a2 = 0, a3 = 0;
            #pragma unroll
            for (int it = 0; it < 4; ++it) {
                int j = it * 64 + lane;
                float a = b1[j];
                a0 += a * lds[j*4+0]; a1 += a * lds[j*4+1];
                a2 += a * lds[j*4+2]; a3 += a * lds[j*4+3];
            }
            #pragma unroll
            for (int off = 32; off > 0; off >>= 1) {
                a0 += __shfl_down(a0, off, 64); a1 += __shfl_down(a1, off, 64);
                a2 += __shfl_down(a2, off, 64); a3 += __shfl_down(a3, off, 64);
            }
            if (lane == 0) {
                c2[q*4+0] = a0; c2[q*4+1] = a1;
                c2[q*4+2] = a2; c2[q*4+3] = a3;
            }
        }
        return;
    }

    // ---- replica fold: 80 nodes/block, 8 rgroups x 16 replicas ------------
    const int j = tid & 127, rg = tid >> 7;
    const int i = b * FOLD_C + j;
    const bool act = (j < FOLD_C) && (i < N);
    float sv = 0.f;
    if (act) {
        size_t st; const float* pp;
        if (i < R0) { st = R0;               pp = part + i; }
        else        { st = (size_t)(N - R0); pp = part + (size_t)NSL * R0 + (i - R0); }
        pp += (size_t)rg * 16 * st;
        #pragma unroll
        for (int r = 0; r < 16; ++r) sv += pp[(size_t)r * st];
    }
    lds[rg * 128 + j] = sv;
    __syncthreads();
    float ui = 0.f;
    if (rg == 0) {
        float tot = 0.f;
        #pragma unroll
        for (int q = 0; q < 8; ++q) tot += lds[q * 128 + j];
        if (act) {
            if (mode == 0) dinv[i] = rsqrtf(tot + 1.0f);          // +1 self-loop
            else { float d = dinv[i]; ui = d * (tot + d); du[i] = d * ui; }
        }
    }
    if (mode == 1) {                             // S_u partial per block
        float v = ui;
        #pragma unroll
        for (int off = 32; off > 0; off >>= 1) v += __shfl_down(v, off, 64);
        if ((tid & 63) == 0) lds[1028 + (tid >> 6)] = v;
        __syncthreads();
        if (tid == 0) {
            float t2 = 0.f;
            #pragma unroll
            for (int q = 0; q < 16; ++q) t2 += lds[1028 + q];
            S_u_part[b] = t2;
        }
    }
}

// ---- contraction: fold wv for tile b (128 nodes), contract against x ------
// 157 blocks x 1024 threads, barrier-free.
__global__ __launch_bounds__(1024) void k_contract(
    const float* __restrict__ x, const float* __restrict__ part,
    const float* __restrict__ dinv, const float* __restrict__ du,
    float* __restrict__ s_part, int N) {
    __shared__ float sh[1024];
    __shared__ float wvl[128];
    const int b = blockIdx.x, tid = threadIdx.x;
    const int k = tid & 127, rg = tid >> 7;      // rg in [0,8)
    const int i0 = b * 128;
    const int i = i0 + k;
    const bool act = i < N;
    // replica fold: 16 strided loads/thread
    float sv = 0.f;
    if (act) {
        size_t st; const float* pp;
        if (i < R0) { st = R0;               pp = part + i; }
        else        { st = (size_t)(N - R0); pp = part + (size_t)NSL * R0 + (i - R0); }
        pp += (size_t)rg * 16 * st;
        #pragma unroll
        for (int r = 0; r < 16; ++r) sv += pp[(size_t)r * st];
    }
    sh[tid] = sv;
    __syncthreads();
    if (rg == 0) {
        float q = 0.f;
        #pragma unroll
        for (int t2 = 0; t2 < 8; ++t2) q += sh[t2 * 128 + k];
        float d = act ? dinv[i] : 0.f;
        wvl[k] = act ? d * (q + du[i]) : 0.f;    // wv = dinv*q + dinv^2*u
    }
    __syncthreads();
    // contraction: 16 unrolled rows/thread, index clamped (wvl==0 masks)
    float a = 0.f;
    #pragma unroll
    for (int jj = 0; jj < 16; ++jj) {
        int m = rg + 8 * jj;
        int i2 = i0 + m;
        float xv = x[(size_t)(i2 < N ? i2 : i0) * D_IN + k];
        a += wvl[m] * xv;
    }
    sh[tid] = a;
    __syncthreads();
    if (rg == 0) {
        float t2s = 0.f;
        #pragma unroll
        for (int t2 = 0; t2 < 8; ++t2) t2s += sh[t2 * 128 + k];
        s_part[b * 128 + k] = t2s;
    }
}

// ---- head: fold s + S_u, g = s@M, z = relu(g@Wd1), logits, softmax --------
// ONE block x 1024 threads (~0.1 MFLOP + ~340 KB reads).
__global__ __launch_bounds__(1024) void k_head(
    const float* __restrict__ s_part, const float* __restrict__ S_u_part,
    const float* __restrict__ M, const float* __restrict__ c2,
    const float* __restrict__ b2, const float* __restrict__ Wd1,
    const float* __restrict__ bd1, const float* __restrict__ Wd2,
    const float* __restrict__ bd2, float* __restrict__ out, float inv_n) {
    __shared__ float sh[1024];
    __shared__ float ss[128];
    __shared__ float gv[256];
    __shared__ float zz[128];
    __shared__ float su[16];
    __shared__ float S_u_s;
    const int tid = threadIdx.x;
    const int k = tid & 127, rg = tid >> 7;      // rg in [0,8)

    // ---- fold s_part over 157 tiles; S_u over 250 partials concurrently ---
    float a2 = 0.f;
    for (int q = rg; q < NTILE; q += 8) a2 += s_part[q * 128 + k];
    float v = (tid < NFOLD) ? S_u_part[tid] : 0.f;
    #pragma unroll
    for (int off = 32; off > 0; off >>= 1) v += __shfl_down(v, off, 64);
    sh[tid] = a2;
    if ((tid & 63) == 0) su[tid >> 6] = v;
    __syncthreads();
    if (rg == 0) {
        float t2 = 0.f;
        #pragma unroll
        for (int q = 0; q < 8; ++q) t2 += sh[q * 128 + k];
        ss[k] = t2;                              // s[k]
    }
    if (tid == 0) {
        float t2 = 0.f;
        #pragma unroll
        for (int q = 0; q < 16; ++q) t2 += su[q];
        S_u_s = t2;
    }
    __syncthreads();

    // ---- g[t] = (sum_k ss[k]*M[k*256+t] + S_u*c2[t])*inv_n + b2[t] --------
    {
        const int t = tid & 255, p = tid >> 8;   // p in [0,4): k-range p*32..
        float gp = 0.f;
        #pragma unroll
        for (int kk = 0; kk < 32; ++kk)
            gp += ss[p * 32 + kk] * M[(p * 32 + kk) * 256 + t];
        sh[tid] = gp;
    }
    __syncthreads();
    if (tid < 256) {
        float gval = sh[tid] + sh[256 + tid] + sh[512 + tid] + sh[768 + tid];
        gv[tid] = (gval + S_u_s * c2[tid]) * inv_n + b2[tid];
    }
    __syncthreads();

    // ---- z[j] = relu(sum_t gv[t]*Wd1[t*128+j] + bd1[j]) -------------------
    {
        const int j = tid & 127, p = tid >> 7;   // p in [0,8): t-range p*32..
        float zp = 0.f;
        #pragma unroll
        for (int t2 = 0; t2 < 32; ++t2)
            zp += gv[p * 32 + t2] * Wd1[(p * 32 + t2) * D_DENSE + j];
        sh[tid] = zp;
    }
    __syncthreads();
    if (tid < 128) {
        float z = bd1[tid];
        #pragma unroll
        for (int p2 = 0; p2 < 8; ++p2) z += sh[p2 * 128 + tid];
        zz[tid] = fmaxf(z, 0.f);
    }
    __syncthreads();

    // ---- logits + softmax -------------------------------------------------
    float p0 = 0.f, p1 = 0.f;
    if (tid < 128) {
        p0 = zz[tid] * Wd2[tid * 2 + 0];
        p1 = zz[tid] * Wd2[tid * 2 + 1];
    }
    #pragma unroll
    for (int off = 32; off > 0; off >>= 1) {
        p0 += __shfl_down(p0, off, 64);
        p1 += __shfl_down(p1, off, 64);
    }
    if ((tid & 63) == 0) { sh[tid >> 6] = p0; sh[32 + (tid >> 6)] = p1; }
    __syncthreads();
    if (tid == 0) {
        float l0 = bd2[0], l1 = bd2[1];
        #pragma unroll
        for (int q = 0; q < 16; ++q) { l0 += sh[q]; l1 += sh[32 + q]; }
        float m = fmaxf(l0, l1);
        float e0 = expf(l0 - m), e1 = expf(l1 - m);
        float inv = 1.0f / (e0 + e1);
        out[0] = e0 * inv;
        out[1] = e1 * inv;
    }
}

extern "C" void kernel_launch(void* const* d_in, const int* in_sizes, int n_in,
                              void* d_out, int out_size, void* d_ws, size_t ws_size,
                              hipStream_t stream) {
    const float* x   = (const float*)d_in[0];
    const int*   ei  = (const int*)  d_in[1];
    const float* w   = (const float*)d_in[2];
    const float* W1  = (const float*)d_in[3];
    const float* b1  = (const float*)d_in[4];
    const float* W2  = (const float*)d_in[5];
    const float* b2  = (const float*)d_in[6];
    const float* Wd1 = (const float*)d_in[7];
    const float* bd1 = (const float*)d_in[8];
    const float* Wd2 = (const float*)d_in[9];
    const float* bd2 = (const float*)d_in[10];
    float* out = (float*)d_out;

    const int N = in_sizes[0] / D_IN;      // 20000
    const int E = in_sizes[1] / 2;         // 640000
    const int* row = ei;
    const int* col = ei + E;

    // workspace layout (every word written before read; no ctr, no memset)
    float* fws    = (float*)d_ws;
    float* part   = fws;                                   // NSL*N = 2.56M
    float* dinv   = part + (size_t)NSL * N;                // N
    float* du     = dinv + N;                              // N (dinv*u)
    float* s_part = du + N;                                // NTILE*128
    float* S_u_p  = s_part + (size_t)NTILE * D_IN;         // NFOLD
    float* M      = S_u_p + NFOLD;                         // 128*256
    float* c2     = M + D_IN * D_HID;                      // 256

    // pass 1: deg by col -> dinv; spare fold blocks compute M=W1@W2, c2=b1@W2
    k_scatter<<<2 * NSL, 1024, 0, stream>>>(col, row, w, dinv, du, part, E, N, 0);
    k_fold<<<NFOLD + 64, 1024, 0, stream>>>(part, dinv, du, S_u_p, W1, b1, W2, M, c2, N, 0);
    // pass 2: by row, gather dinv[col] -> du, S_u partials
    k_scatter<<<2 * NSL, 1024, 0, stream>>>(row, col, w, dinv, du, part, E, N, 1);
    k_fold<<<NFOLD, 1024, 0, stream>>>(part, dinv, du, S_u_p, W1, b1, W2, M, c2, N, 1);
    // pass 3: by row, gather du[col] (single gather)
    k_scatter<<<2 * NSL, 1024, 0, stream>>>(row, col, w, dinv, du, part, E, N, 2);
    // wv-fold + feature contraction (barrier-free), then 1-block head
    k_contract<<<NTILE, 1024, 0, stream>>>(x, part, dinv, du, s_part, N);
    k_head<<<1, 1024, 0, stream>>>(s_part, S_u_p, M, c2, b2, Wd1, bd1, Wd2, bd2,
                                   out, 1.0f / (float)N);
}